// Round 11
// baseline (322.267 us; speedup 1.0000x reference)
//
#include <hip/hip_runtime.h>
#include <hip/hip_bf16.h>
#include <math.h>

typedef __bf16 bf16_t;
typedef __bf16 bf16x4 __attribute__((ext_vector_type(4)));
typedef __bf16 bf16x8 __attribute__((ext_vector_type(8)));
typedef float f32x4 __attribute__((ext_vector_type(4)));

#define LOG2E 1.4426950408889634f

typedef const __attribute__((address_space(1))) void* as1cv;
typedef __attribute__((address_space(3))) void* as3v;

__device__ __forceinline__ void gload16(const bf16_t* g, bf16_t* l) {
  __builtin_amdgcn_global_load_lds((as1cv)g, (as3v)l, 16, 0, 0);
}

// ============ fused prep: xconv + ALL 5 weight transposes, one launch =========
__global__ __launch_bounds__(256)
void prep_k(const float* __restrict__ x, const float* __restrict__ Wqd,
            const float* __restrict__ Wkvd, const float* __restrict__ Wqu,
            const float* __restrict__ Wkvu, const float* __restrict__ Wout,
            bf16_t* __restrict__ xb, bf16_t* __restrict__ WdT,
            bf16_t* __restrict__ WquT, bf16_t* __restrict__ WkvuT,
            bf16_t* __restrict__ WoutT) {
  __shared__ float t[32][33];
  const int tid = threadIdx.x;
  int bid = blockIdx.x;
  if (bid < 4096) {
    int i = (bid * 256 + tid) * 4;
    float4 v = *(const float4*)(x + i);
    bf16x4 o;
    o[0] = (bf16_t)v.x; o[1] = (bf16_t)v.y; o[2] = (bf16_t)v.z; o[3] = (bf16_t)v.w;
    *(bf16x4*)(xb + i) = o;
    return;
  }
  bid -= 4096;
  const float* in; bf16_t* out; int C, R, bx, by;
  if (bid < 3072)       { in = Wqd;  out = WdT;           R = 2048; C = 1536; bx = bid % 48;  by = bid / 48; }
  else if (bid < 4224)  { int b = bid - 3072;  in = Wkvd; out = WdT + 3145728; R = 2048; C = 576;  bx = b % 18;  by = b / 18; }
  else if (bid < 8832)  { int b = bid - 4224;  in = Wqu;  out = WquT;  R = 1536; C = 3072; bx = b % 96;  by = b / 96; }
  else if (bid < 10880) { int b = bid - 8832;  in = Wkvu; out = WkvuT; R = 512;  C = 4096; bx = b % 128; by = b / 128; }
  else                  { int b = bid - 10880; in = Wout; out = WoutT; R = 2048; C = 2048; bx = b % 64;  by = b / 64; }
  const int c0 = bx * 32, r0 = by * 32;
  const int tx = tid & 31, ty = tid >> 5;
#pragma unroll
  for (int i = 0; i < 32; i += 8)
    t[ty + i][tx] = in[(size_t)(r0 + ty + i) * C + c0 + tx];
  __syncthreads();
#pragma unroll
  for (int i = 0; i < 32; i += 8)
    out[(size_t)(c0 + ty + i) * R + r0 + tx] = (bf16_t)t[tx][ty + i];
}

#define VMCNT(n) asm volatile("s_waitcnt vmcnt(" #n ")" ::: "memory")

// ======== 8-wave, counted-vmcnt double-buffered 128x128 GEMM core =============
// (unchanged — T2 swizzle + T4 counted vmcnt, verified rounds 2-4; qkvup only)

__device__ __forceinline__ void stage8(const bf16_t* __restrict__ A,
                                       const bf16_t* __restrict__ Bt,
                                       int K, int N, int m0, int n0, int k0,
                                       bf16_t* As, bf16_t* Bs,
                                       int wave, int srow, int scol) {
#pragma unroll
  for (int i = 0; i < 2; ++i) {
    int r0 = (wave * 2 + i) * 8;
    gload16(A + (size_t)(m0 + r0 + srow) * K + k0 + scol, As + r0 * 64);
    int br = n0 + r0 + srow;
    if (br >= N) br = N - 1;
    gload16(Bt + (size_t)br * K + k0 + scol, Bs + r0 * 64);
  }
}

__device__ __forceinline__ void compute8(const bf16_t* As, const bf16_t* Bs,
                                         f32x4 (&acc)[2][4],
                                         int lane, int wr, int wc) {
  const int lm = lane & 15;
  const int sw = lm & 7;
#pragma unroll
  for (int ks = 0; ks < 2; ++ks) {
    const int ck = ((lane >> 4) + ks * 4) ^ sw;  // swizzled 16B chunk slot
    bf16x8 af[2], bfr[4];
#pragma unroll
    for (int i = 0; i < 2; ++i)
      af[i] = *(const bf16x8*)(As + (wr + i * 16 + lm) * 64 + ck * 8);
#pragma unroll
    for (int i = 0; i < 4; ++i)
      bfr[i] = *(const bf16x8*)(Bs + (wc + i * 16 + lm) * 64 + ck * 8);
#pragma unroll
    for (int mi = 0; mi < 2; ++mi)
#pragma unroll
      for (int ni = 0; ni < 4; ++ni)
        acc[mi][ni] = __builtin_amdgcn_mfma_f32_16x16x32_bf16(
            af[mi], bfr[ni], acc[mi][ni], 0, 0, 0);
  }
}

__device__ __forceinline__ void gemm128_dbuf8(const bf16_t* __restrict__ A,
                                              const bf16_t* __restrict__ Bt,
                                              int K, int N, int m0, int n0,
                                              bf16_t* lds, f32x4 (&acc)[2][4],
                                              int wave, int lane) {
  const int srow = lane >> 3;
  const int scol = ((lane & 7) ^ srow) * 8;  // pre-swizzled global source
  const int wr = (wave >> 1) * 32, wc = (wave & 1) * 64;
  bf16_t* A0 = lds;
  bf16_t* B0 = lds + 8192;
  bf16_t* A1 = lds + 16384;
  bf16_t* B1 = lds + 24576;
  const int nk = K >> 6;  // even, >= 2
  stage8(A, Bt, K, N, m0, n0, 0, A0, B0, wave, srow, scol);
  stage8(A, Bt, K, N, m0, n0, 64, A1, B1, wave, srow, scol);
  VMCNT(4);
  __builtin_amdgcn_s_barrier();
#pragma unroll 1
  for (int t = 0; t < nk; t += 2) {
    compute8(A0, B0, acc, lane, wr, wc);
    __builtin_amdgcn_s_barrier();
    if (t + 2 < nk) {
      stage8(A, Bt, K, N, m0, n0, (t + 2) << 6, A0, B0, wave, srow, scol);
      VMCNT(4);
    } else {
      VMCNT(0);
    }
    __builtin_amdgcn_s_barrier();
    compute8(A1, B1, acc, lane, wr, wc);
    if (t + 3 <= nk) {
      __builtin_amdgcn_s_barrier();
      if (t + 3 < nk) {
        stage8(A, Bt, K, N, m0, n0, (t + 3) << 6, A1, B1, wave, srow, scol);
        VMCNT(4);
      } else {
        VMCNT(0);
      }
      __builtin_amdgcn_s_barrier();
    }
  }
}

// ======== NEW: 8-wave 64x128 GEMM core (dn8/outf8 grid-supply fix) ===========
// r10 lesson: dn8 (272 blocks) and outf8 (256) sat at 1.0 block/CU — the
// latency-starved regime. 64x128 tiles double their grids (544/512, ~2.1/CU);
// LDS 48KB -> 3 blocks/CU capacity. Same T2 swizzle + T4 counted vmcnt; 3
// gloads/wave/stage -> vmcnt(3). Wave tile 32x32 (2M x 4N waves), acc[2][2].

__device__ __forceinline__ void stage64(const bf16_t* __restrict__ A,
                                        const bf16_t* __restrict__ Bt,
                                        int K, int N, int m0, int n0, int k0,
                                        bf16_t* As, bf16_t* Bs,
                                        int wave, int srow, int scol) {
  gload16(A + (size_t)(m0 + wave * 8 + srow) * K + k0 + scol, As + wave * 512);
#pragma unroll
  for (int i = 0; i < 2; ++i) {
    int r0 = (wave * 2 + i) * 8;
    int br = n0 + r0 + srow;
    if (br >= N) br = N - 1;
    gload16(Bt + (size_t)br * K + k0 + scol, Bs + r0 * 64);
  }
}

__device__ __forceinline__ void compute64(const bf16_t* As, const bf16_t* Bs,
                                          f32x4 (&acc)[2][2],
                                          int lane, int wr, int wc) {
  const int lm = lane & 15;
  const int sw = lm & 7;
#pragma unroll
  for (int ks = 0; ks < 2; ++ks) {
    const int ck = ((lane >> 4) + ks * 4) ^ sw;
    bf16x8 af[2], bfr[2];
#pragma unroll
    for (int i = 0; i < 2; ++i)
      af[i] = *(const bf16x8*)(As + (wr + i * 16 + lm) * 64 + ck * 8);
#pragma unroll
    for (int i = 0; i < 2; ++i)
      bfr[i] = *(const bf16x8*)(Bs + (wc + i * 16 + lm) * 64 + ck * 8);
#pragma unroll
    for (int mi = 0; mi < 2; ++mi)
#pragma unroll
      for (int ni = 0; ni < 2; ++ni)
        acc[mi][ni] = __builtin_amdgcn_mfma_f32_16x16x32_bf16(
            af[mi], bfr[ni], acc[mi][ni], 0, 0, 0);
  }
}

__device__ __forceinline__ void gemm64_dbuf8(const bf16_t* __restrict__ A,
                                             const bf16_t* __restrict__ Bt,
                                             int K, int N, int m0, int n0,
                                             bf16_t* lds, f32x4 (&acc)[2][2],
                                             int wave, int lane) {
  const int srow = lane >> 3;
  const int scol = ((lane & 7) ^ srow) * 8;
  const int wr = (wave >> 2) * 32, wc = (wave & 3) * 32;
  bf16_t* A0 = lds;            // 64x64  = 4096 el
  bf16_t* B0 = lds + 4096;     // 128x64 = 8192 el
  bf16_t* A1 = lds + 12288;
  bf16_t* B1 = lds + 16384;
  const int nk = K >> 6;  // even (32 for K=2048)
  stage64(A, Bt, K, N, m0, n0, 0, A0, B0, wave, srow, scol);
  stage64(A, Bt, K, N, m0, n0, 64, A1, B1, wave, srow, scol);
  VMCNT(3);
  __builtin_amdgcn_s_barrier();
#pragma unroll 1
  for (int t = 0; t < nk; t += 2) {
    compute64(A0, B0, acc, lane, wr, wc);
    __builtin_amdgcn_s_barrier();
    if (t + 2 < nk) {
      stage64(A, Bt, K, N, m0, n0, (t + 2) << 6, A0, B0, wave, srow, scol);
      VMCNT(3);
    } else {
      VMCNT(0);
    }
    __builtin_amdgcn_s_barrier();
    compute64(A1, B1, acc, lane, wr, wc);
    if (t + 3 <= nk) {
      __builtin_amdgcn_s_barrier();
      if (t + 3 < nk) {
        stage64(A, Bt, K, N, m0, n0, (t + 3) << 6, A1, B1, wave, srow, scol);
        VMCNT(3);
      } else {
        VMCNT(0);
      }
      __builtin_amdgcn_s_barrier();
    }
  }
}

// ---- down-proj: bf16 output with col guard (N=2112), 64x128 tiles ------------
__global__ __launch_bounds__(512)
void gemm_dn8(const bf16_t* __restrict__ A, const bf16_t* __restrict__ Bt,
              bf16_t* __restrict__ C, int M, int N, int K) {
  __shared__ __align__(16) bf16_t lds[24576];
  const int tid = threadIdx.x;
  const int wave = tid >> 6, lane = tid & 63;
  const int m0 = blockIdx.y * 64, n0 = blockIdx.x * 128;
  const int wr = (wave >> 2) * 32, wc = (wave & 3) * 32;
  f32x4 acc[2][2] = {};
  gemm64_dbuf8(A, Bt, K, N, m0, n0, lds, acc, wave, lane);
  const int lm = lane & 15, lr = (lane >> 4) * 4;
#pragma unroll
  for (int mi = 0; mi < 2; ++mi)
#pragma unroll
    for (int ni = 0; ni < 2; ++ni) {
      int col = n0 + wc + ni * 16 + lm;
      if (col < N) {
#pragma unroll
        for (int i = 0; i < 4; ++i) {
          int row = m0 + wr + mi * 16 + lr + i;
          C[(size_t)row * N + col] = (bf16_t)acc[mi][ni][i];
        }
      }
    }
}

// ---- out-proj: f32 output (N=2048 exact), 64x128 tiles -----------------------
__global__ __launch_bounds__(512)
void gemm_outf8(const bf16_t* __restrict__ A, const bf16_t* __restrict__ Bt,
                float* __restrict__ C, int M, int N, int K) {
  __shared__ __align__(16) bf16_t lds[24576];
  const int tid = threadIdx.x;
  const int wave = tid >> 6, lane = tid & 63;
  const int m0 = blockIdx.y * 64, n0 = blockIdx.x * 128;
  const int wr = (wave >> 2) * 32, wc = (wave & 3) * 32;
  f32x4 acc[2][2] = {};
  gemm64_dbuf8(A, Bt, K, N, m0, n0, lds, acc, wave, lane);
  const int lm = lane & 15, lr = (lane >> 4) * 4;
#pragma unroll
  for (int mi = 0; mi < 2; ++mi)
#pragma unroll
    for (int ni = 0; ni < 2; ++ni) {
      int col = n0 + wc + ni * 16 + lm;
#pragma unroll
      for (int i = 0; i < 4; ++i) {
        int row = m0 + wr + mi * 16 + lr + i;
        C[(size_t)row * N + col] = acc[mi][ni][i];
      }
    }
}

// ---- merged q_up (fused RoPE/pack) + kv_up (fused k_nope/V-T pack) -----------
__global__ __launch_bounds__(512)
void gemm_qkvup8(const bf16_t* __restrict__ qdn, const bf16_t* __restrict__ WquT,
                 const bf16_t* __restrict__ ckvn, const bf16_t* __restrict__ WkvuT,
                 const int* __restrict__ pos, bf16_t* __restrict__ qs,
                 bf16_t* __restrict__ ks, bf16_t* __restrict__ vt) {
  __shared__ __align__(16) bf16_t lds[32768];
  const int tid = threadIdx.x;
  const int wave = tid >> 6, lane = tid & 63;
  const int m0 = blockIdx.y * 128;
  const int wr = (wave >> 1) * 32, wc = (wave & 1) * 64;
  const int lm = lane & 15, lr = (lane >> 4) * 4;
  f32x4 acc[2][4] = {};
  if (blockIdx.x < 24) {
    const int n0 = blockIdx.x * 128;
    gemm128_dbuf8(qdn, WquT, 1536, 3072, m0, n0, lds, acc, wave, lane);
    const bool rope = (((n0 + wc) / 64) % 3) == 2;
    if (rope) {
#pragma unroll
      for (int mi = 0; mi < 2; ++mi)
#pragma unroll
        for (int i = 0; i < 4; ++i) {
          int row = m0 + wr + mi * 16 + lr + i;
          float p = (float)pos[row];
#pragma unroll
          for (int nl = 0; nl < 2; ++nl) {
            int fi = nl * 16 + lm;
            float ang = p * exp2f(-(float)fi * 0.41524101186092030f);
            float sn, cs;
            sincosf(ang, &sn, &cs);
            float v0 = acc[mi][nl][i], v1 = acc[mi][nl + 2][i];
            int c = n0 + wc + nl * 16 + lm;
            int h = c / 192, d = c - h * 192;  // d = 128+fi
            bf16_t* base = qs + ((size_t)h * 2048 + row) * 192;
            base[d]      = (bf16_t)(v0 * cs - v1 * sn);
            base[d + 32] = (bf16_t)(v1 * cs + v0 * sn);
          }
        }
    } else {
#pragma unroll
      for (int mi = 0; mi < 2; ++mi)
#pragma unroll
        for (int ni = 0; ni < 4; ++ni) {
          int c = n0 + wc + ni * 16 + lm;
          int h = c / 192, d = c - h * 192;
#pragma unroll
          for (int i = 0; i < 4; ++i) {
            int row = m0 + wr + mi * 16 + lr + i;
            qs[((size_t)h * 2048 + row) * 192 + d] = (bf16_t)acc[mi][ni][i];
          }
        }
    }
  } else {
    const int n0 = (blockIdx.x - 24) * 128;
    gemm128_dbuf8(ckvn, WkvuT, 512, 4096, m0, n0, lds, acc, wave, lane);
#pragma unroll
    for (int mi = 0; mi < 2; ++mi)
#pragma unroll
      for (int ni = 0; ni < 4; ++ni) {
        int c = n0 + wc + ni * 16 + lm;
        int h = c >> 8, j = c & 255;
#pragma unroll
        for (int i = 0; i < 4; ++i) {
          int row = m0 + wr + mi * 16 + lr + i;
          bf16_t v = (bf16_t)acc[mi][ni][i];
          if (j < 128)
            ks[((size_t)h * 2048 + row) * 192 + j] = v;
          else
            vt[((size_t)h * 128 + (j - 128)) * 2048 + row] = v;
        }
      }
  }
}

// ---------------- merged: rmsnorm(q) + rmsnorm(kv) + k-rope -------------------
__global__ __launch_bounds__(256)
void normrope_k(const bf16_t* __restrict__ Cd, const float* __restrict__ qnw,
                const float* __restrict__ kvnw, const int* __restrict__ pos,
                bf16_t* __restrict__ qdn, bf16_t* __restrict__ ckvn,
                bf16_t* __restrict__ ks) {
  __shared__ float red[4];
  const int bid = blockIdx.x, tid = threadIdx.x;
  if (bid < 4096) {
    const bf16_t* xr;
    const float* W;
    bf16_t* yr;
    int C;
    if (bid < 2048) {
      xr = Cd + (size_t)bid * 2112; W = qnw; yr = qdn + (size_t)bid * 1536; C = 1536;
    } else {
      int r = bid - 2048;
      xr = Cd + (size_t)r * 2112 + 1536; W = kvnw; yr = ckvn + (size_t)r * 512; C = 512;
    }
    int nch = C >> 3;
    bool act = tid < nch;
    float xv[8];
    float ss = 0.f;
    if (act) {
      bf16x8 v = *(const bf16x8*)(xr + tid * 8);
#pragma unroll
      for (int i = 0; i < 8; ++i) { xv[i] = (float)v[i]; ss += xv[i] * xv[i]; }
    }
#pragma unroll
    for (int off = 1; off < 64; off <<= 1) ss += __shfl_xor(ss, off, 64);
    if ((tid & 63) == 0) red[tid >> 6] = ss;
    __syncthreads();
    float tot = red[0] + red[1] + red[2] + red[3];
    float rs = rsqrtf(tot / (float)C + 1e-6f);
    if (act) {
      bf16x8 o;
#pragma unroll
      for (int i = 0; i < 8; ++i) {
        bf16_t nb = (bf16_t)(xv[i] * rs);
        o[i] = (bf16_t)((float)nb * W[tid * 8 + i]);
      }
      *(bf16x8*)(yr + tid * 8) = o;
    }
  } else {
    int s = bid - 4096, d = tid;
    if (d < 64) {
      float v = (float)Cd[(size_t)s * 2112 + 2048 + d];
      int fi = d & 31;
      float p = (float)pos[s];
      float ang = p * exp2f(-(float)fi * 0.415241011860920295f);
      float sn = sinf(ang), co = cosf(ang);
      float other = (float)Cd[(size_t)s * 2112 + 2048 + (d < 32 ? d + 32 : d - 32)];
      v = (d < 32) ? v * co - other * sn : v * co + other * sn;
      bf16_t bv = (bf16_t)v;
#pragma unroll
      for (int h = 0; h < 16; ++h)
        ks[((size_t)h * 2048 + s) * 192 + 128 + d] = bv;
    }
  }
}

// ---------------- flash attention (round-8 body, 56.3us known-good) -----------
// swapped-QK + packed b64 P-writes; 128-row Q-tiles; paired schedule; split at
// k-tile 16 with additive combine. 60KB LDS, 2 barriers/iter, natural regalloc.
__global__ __launch_bounds__(256, 2)
void attn3_k(const bf16_t* __restrict__ Q, const bf16_t* __restrict__ Kst,
             const bf16_t* __restrict__ Vt, bf16_t* __restrict__ O,
             float* __restrict__ pbuf) {
  __shared__ __align__(16) bf16_t Ks[64 * 192];
  __shared__ __align__(16) bf16_t Vs[144 * 64];
  __shared__ __align__(16) bf16_t Ps[4][32 * 72];
  const int bid = blockIdx.x;
  int h, T, kbeg, kend, sp = 1;
  bool direct = false;
  if (bid < 128) {            // heavy pair-member
    h = bid >> 3; int u = bid & 7; int up = u >> 1;
    if ((u & 1) == 0) { T = 7 - up;  kbeg = 0;  kend = 2 * T + 2; direct = true; }
    else              { T = 15 - up; kbeg = 16; kend = 2 * T + 2; }
  } else if (bid < 256) {     // single: chunk0 of T>=8
    h = (bid - 128) >> 3; T = 8 + ((bid - 128) & 7); kbeg = 0; kend = 16; sp = 0;
  } else {                    // light pair-member
    h = (bid - 256) >> 3; int u = (bid - 256) & 7; int up = u >> 1;
    if ((u & 1) == 0) { T = up;     kbeg = 0;  kend = 2 * T + 2; direct = true; }
    else              { T = 8 + up; kbeg = 16; kend = 2 * T + 2; }
  }
  const int q0 = T * 128;
  const int tid = threadIdx.x, wave = tid >> 6, lane = tid & 63;
  const int lm = lane & 15, lg = lane >> 4;
  const bf16_t* Qh = Q + (size_t)h * 2048 * 192;
  const bf16_t* Kh = Kst + (size_t)h * 2048 * 192;
  const bf16_t* Vh = Vt + (size_t)h * 128 * 2048;
  const float sc = 0.08838834764831845f * LOG2E;

  bf16x8 aq[2][6];
#pragma unroll
  for (int g = 0; g < 2; ++g)
#pragma unroll
    for (int tt = 0; tt < 6; ++tt)
      aq[g][tt] = *(const bf16x8*)(Qh +
          (size_t)(q0 + wave * 32 + g * 16 + lm) * 192 + tt * 32 + lg * 8);

#pragma unroll
  for (int w = 0; w < 4; ++w) {
    int idx = w * 256 + tid;
    Vs[128 * 64 + idx] = (bf16_t)(idx < 64 ? 1.0f : 0.0f);
  }

  int kr[6], kc8[6], vr[4], vc8[4];
#pragma unroll
  for (int w = 0; w < 6; ++w) {
    int s = (wave * 6 + w) * 64 + lane;
    kr[w] = s / 24;
    kc8[w] = ((s % 24) ^ (kr[w] & 7)) * 8;
  }
#pragma unroll
  for (int w = 0; w < 4; ++w) {
    int s = (wave * 4 + w) * 64 + lane;
    vr[w] = s >> 3;
    vc8[w] = ((s & 7) ^ (vr[w] & 7)) * 8;
  }

  bf16x8 kstg[6], vstg[4];
  const int kb0 = kbeg * 64;
#pragma unroll
  for (int w = 0; w < 6; ++w)
    kstg[w] = *(const bf16x8*)(Kh + (size_t)(kb0 + kr[w]) * 192 + kc8[w]);
#pragma unroll
  for (int w = 0; w < 4; ++w)
    vstg[w] = *(const bf16x8*)(Vh + (size_t)vr[w] * 2048 + kb0 + vc8[w]);

  f32x4 o[2][9] = {};

  for (int kt = kbeg; kt < kend; ++kt) {
    const int k0 = kt * 64;
    if (kt != kbeg) __syncthreads();
#pragma unroll
    for (int w = 0; w < 6; ++w)
      *(bf16x8*)(Ks + ((wave * 6 + w) * 64 + lane) * 8) = kstg[w];
#pragma unroll
    for (int w = 0; w < 4; ++w)
      *(bf16x8*)(Vs + ((wave * 4 + w) * 64 + lane) * 8) = vstg[w];
    __syncthreads();

    if (kt + 1 < kend) {
      const int k1 = k0 + 64;
#pragma unroll
      for (int w = 0; w < 6; ++w)
        kstg[w] = *(const bf16x8*)(Kh + (size_t)(k1 + kr[w]) * 192 + kc8[w]);
#pragma unroll
      for (int w = 0; w < 4; ++w)
        vstg[w] = *(const bf16x8*)(Vh + (size_t)vr[w] * 2048 + k1 + vc8[w]);
    }

    // QK^T, SWAPPED operands: sa[g][ct] = C[k][q] (k-rows, q-cols).
    f32x4 sa[2][4] = {};
    __builtin_amdgcn_s_setprio(1);
#pragma unroll
    for (int ct = 0; ct < 4; ++ct) {
#pragma unroll
      for (int tt = 0; tt < 6; ++tt) {
        int cc = (tt * 4 + lg) ^ (lm & 7);
        bf16x8 bk = *(const bf16x8*)(Ks + (ct * 16 + lm) * 192 + cc * 8);
        sa[0][ct] = __builtin_amdgcn_mfma_f32_16x16x32_bf16(bk, aq[0][tt], sa[0][ct], 0, 0, 0);
        sa[1][ct] = __builtin_amdgcn_mfma_f32_16x16x32_bf16(bk, aq[1][tt], sa[1][ct], 0, 0, 0);
      }
    }
    __builtin_amdgcn_s_setprio(0);

    // P = exp2(sa*sc), masked, packed to b64 writes (4 k-contiguous per lane).
    bf16_t* Pw = Ps[wave];
    const bool diag = (kt >= 2 * T);
#pragma unroll
    for (int g = 0; g < 2; ++g) {
      const int gq = q0 + wave * 32 + g * 16 + lm;  // this lane's q-row
#pragma unroll
      for (int ct = 0; ct < 4; ++ct) {
        bf16x4 pk;
#pragma unroll
        for (int i = 0; i < 4; ++i) {
          float p = exp2f(sa[g][ct][i] * sc);
          if (diag && (k0 + ct * 16 + lg * 4 + i > gq)) p = 0.f;
          pk[i] = (bf16_t)p;
        }
        *(bf16x4*)(Pw + (g * 16 + lm) * 72 + ct * 16 + lg * 4) = pk;
      }
    }
    __builtin_amdgcn_s_waitcnt(0xC07F);

    __builtin_amdgcn_s_setprio(1);
#pragma unroll
    for (int ks2 = 0; ks2 < 2; ++ks2) {
      bf16x8 ap0 = *(const bf16x8*)(Pw + lm * 72 + ks2 * 32 + lg * 8);
      bf16x8 ap1 = *(const bf16x8*)(Pw + (16 + lm) * 72 + ks2 * 32 + lg * 8);
#pragma unroll
      for (int nt = 0; nt < 9; ++nt) {
        int rowv = nt * 16 + lm;
        int cc = (ks2 * 4 + lg) ^ (lm & 7);
        bf16x8 bv = *(const bf16x8*)(Vs + rowv * 64 + cc * 8);
        o[0][nt] = __builtin_amdgcn_mfma_f32_16x16x32_bf16(ap0, bv, o[0][nt], 0, 0, 0);
        o[1][nt] = __builtin_amdgcn_mfma_f32_16x16x32_bf16(ap1, bv, o[1][nt], 0, 0, 0);
      }
    }
    __builtin_amdgcn_s_setprio(0);
  }

  if (direct) {
#pragma unroll
    for (int g = 0; g < 2; ++g)
#pragma unroll
      for (int i = 0; i < 4; ++i) {
        float l = __shfl(o[g][8][i], (lane & 48), 64);
        float inv = 1.f / l;
        int row = q0 + wave * 32 + g * 16 + lg * 4 + i;
#pragma unroll
        for (int nt = 0; nt < 8; ++nt)
          O[(size_t)row * 2048 + h * 128 + nt * 16 + lm] = (bf16_t)(o[g][nt][i] * inv);
      }
  } else {
    float* P = pbuf + ((size_t)(h * 8 + (T - 8)) * 2 + sp) * 16896;
#pragma unroll
    for (int g = 0; g < 2; ++g)
#pragma unroll
      for (int i = 0; i < 4; ++i) {
        int r = wave * 32 + g * 16 + lg * 4 + i;  // 0..127
#pragma unroll
        for (int nt = 0; nt < 8; ++nt)
          P[r * 132 + nt * 16 + lm] = o[g][nt][i];
        if (lm == 0) P[r * 132 + 128] = o[g][8][i];
      }
  }
}

// ---------------- split-K combine: O = (p0+p1)/(l0+l1) ------------------------
__global__ __launch_bounds__(256)
void combine_k(const float* __restrict__ pbuf, bf16_t* __restrict__ O) {
  const int b = blockIdx.x, tid = threadIdx.x;
  const int h = b >> 3, tt = b & 7;
  const int r = tid >> 1, c0 = (tid & 1) * 64;
  const float* p0 = pbuf + ((size_t)(h * 8 + tt) * 2) * 16896 + r * 132;
  const float* p1 = p0 + 16896;
  const float inv = 1.f / (p0[128] + p1[128]);
  const int row = (8 + tt) * 128 + r;
  bf16_t* dst = O + (size_t)row * 2048 + h * 128 + c0;
#pragma unroll
  for (int i = 0; i < 64; i += 4) {
    float4 a = *(const float4*)(p0 + c0 + i);
    float4 c = *(const float4*)(p1 + c0 + i);
    bf16x4 v;
    v[0] = (bf16_t)((a.x + c.x) * inv);
    v[1] = (bf16_t)((a.y + c.y) * inv);
    v[2] = (bf16_t)((a.z + c.z) * inv);
    v[3] = (bf16_t)((a.w + c.w) * inv);
    *(bf16x4*)(dst + i) = v;
  }
}

// ------------------------------------------------------------------------------
// Arena (bf16 elements), lifetime-packed (unchanged):
//   A @0         (4,194,304): xb (dies after dn8)  -> attb (born at attn)
//   B @4194304   (4,325,376): WdT (dies after dn8) -> qdn (dies after qkvup)
//   C @8519680   (4,718,592): WquT (dies after qkvup)
//   D @13238272  (2,097,152): WkvuT (dies after qkvup)
//     pbuf (f32, 17.3MB) overlays B+C+D byte span during attn
//   E @15335424  (4,194,304): WoutT
//   F @19529728  (4,325,376): Cdown (dies after normrope) -> vt
//   G @23855104  (6,291,456): qs
//   H @30146560  (6,291,456): ks
//   I @36438016  (1,048,576): ckvn
extern "C" void kernel_launch(void* const* d_in, const int* in_sizes, int n_in,
                              void* d_out, int out_size, void* d_ws, size_t ws_size,
                              hipStream_t stream) {
  const float* x    = (const float*)d_in[0];
  const int*   pos  = (const int*)d_in[1];
  const float* Wqd  = (const float*)d_in[3];
  const float* qnw  = (const float*)d_in[4];
  const float* Wqu  = (const float*)d_in[5];
  const float* Wkvd = (const float*)d_in[6];
  const float* kvnw = (const float*)d_in[7];
  const float* Wkvu = (const float*)d_in[8];
  const float* Wout = (const float*)d_in[9];
  float* out = (float*)d_out;

  bf16_t* arena = (bf16_t*)d_ws;
  bf16_t* xb    = arena;                // region A
  bf16_t* attb  = arena;                // region A (after xb dies)
  bf16_t* WdT   = arena + 4194304;      // region B
  bf16_t* qdn   = arena + 4194304;      // region B (after WdT dies)
  bf16_t* WquT  = arena + 8519680;      // region C
  bf16_t* WkvuT = arena + 13238272;     // region D
  float*  pbuf  = (float*)(arena + 4194304);  // B..D span, live only in attn
  bf16_t* WoutT = arena + 15335424;     // region E
  bf16_t* Cdown = arena + 19529728;     // region F
  bf16_t* vt    = arena + 19529728;     // region F (after Cdown dies)
  bf16_t* qs    = arena + 23855104;     // region G
  bf16_t* ks    = arena + 30146560;     // region H
  bf16_t* ckvn  = arena + 36438016;     // region I

  // 1) fused prep: xconv + all 5 weight transposes
  prep_k<<<dim3(19072), 256, 0, stream>>>(x, Wqd, Wkvd, Wqu, Wkvu, Wout,
                                          xb, WdT, WquT, WkvuT, WoutT);

  // 2) fused down-projection, 64x128 tiles (544 blocks, ~2.1/CU)
  gemm_dn8<<<dim3(17, 32), 512, 0, stream>>>(xb, WdT, Cdown, 2048, 2112, 2048);

  // 3) norms + k rope
  normrope_k<<<dim3(6144), 256, 0, stream>>>(Cdown, qnw, kvnw, pos, qdn, ckvn, ks);

  // 4) merged q_up + kv_up (128x128 core, 896 blocks)
  gemm_qkvup8<<<dim3(56, 16), 512, 0, stream>>>(qdn, WquT, ckvn, WkvuT, pos,
                                                qs, ks, vt);

  // 5) attention (round-8 body)
  attn3_k<<<dim3(384), 256, 0, stream>>>(qs, ks, vt, attb, pbuf);

  // 6) combine split-tile partials for rows 1024..2047
  combine_k<<<dim3(128), 256, 0, stream>>>(pbuf, attb);

  // 7) output projection, 64x128 tiles (512 blocks, 2/CU)
  gemm_outf8<<<dim3(16, 32), 512, 0, stream>>>(attb, WoutT, out, 2048, 2048, 2048);
}

// Round 12
// 308.243 us; speedup vs baseline: 1.0455x; 1.0455x over previous
//
#include <hip/hip_runtime.h>
#include <hip/hip_bf16.h>
#include <math.h>

typedef __bf16 bf16_t;
typedef __bf16 bf16x4 __attribute__((ext_vector_type(4)));
typedef __bf16 bf16x8 __attribute__((ext_vector_type(8)));
typedef float f32x4 __attribute__((ext_vector_type(4)));

#define LOG2E 1.4426950408889634f

typedef const __attribute__((address_space(1))) void* as1cv;
typedef __attribute__((address_space(3))) void* as3v;

__device__ __forceinline__ void gload16(const bf16_t* g, bf16_t* l) {
  __builtin_amdgcn_global_load_lds((as1cv)g, (as3v)l, 16, 0, 0);
}

// ============ fused prep: xconv + ALL 5 weight transposes, one launch =========
// r11 fix: transpose tiles are 64 input-rows x 32 input-cols. Output rows are
// then 64 contiguous bf16 = 128-BYTE write segments (was 64B = half a line).
// Reads stay 128B (32 f32). LDS t[64][33]: write t[row][col] stride-33 ok;
// read t[ox][oy+j] consecutive ox -> bank = (33*ox+c)%32 = (ox+c)%32 distinct.
__global__ __launch_bounds__(256)
void prep_k(const float* __restrict__ x, const float* __restrict__ Wqd,
            const float* __restrict__ Wkvd, const float* __restrict__ Wqu,
            const float* __restrict__ Wkvu, const float* __restrict__ Wout,
            bf16_t* __restrict__ xb, bf16_t* __restrict__ WdT,
            bf16_t* __restrict__ WquT, bf16_t* __restrict__ WkvuT,
            bf16_t* __restrict__ WoutT) {
  __shared__ float t[64][33];
  const int tid = threadIdx.x;
  int bid = blockIdx.x;
  if (bid < 4096) {
    int i = (bid * 256 + tid) * 4;
    float4 v = *(const float4*)(x + i);
    bf16x4 o;
    o[0] = (bf16_t)v.x; o[1] = (bf16_t)v.y; o[2] = (bf16_t)v.z; o[3] = (bf16_t)v.w;
    *(bf16x4*)(xb + i) = o;
    return;
  }
  bid -= 4096;
  // segments (64x32 tiles): Wqd 48x32=1536 | Wkvd 18x32=576 | Wqu 96x24=2304
  //                         | Wkvu 128x8=1024 | Wout 64x32=2048  -> 7488
  const float* in; bf16_t* out; int C, R, bx, by;
  if (bid < 1536)      { in = Wqd;  out = WdT;           R = 2048; C = 1536; bx = bid % 48;  by = bid / 48; }
  else if (bid < 2112) { int b = bid - 1536; in = Wkvd; out = WdT + 3145728; R = 2048; C = 576;  bx = b % 18;  by = b / 18; }
  else if (bid < 4416) { int b = bid - 2112; in = Wqu;  out = WquT;  R = 1536; C = 3072; bx = b % 96;  by = b / 96; }
  else if (bid < 5440) { int b = bid - 4416; in = Wkvu; out = WkvuT; R = 512;  C = 4096; bx = b % 128; by = b / 128; }
  else                 { int b = bid - 5440; in = Wout; out = WoutT; R = 2048; C = 2048; bx = b % 64;  by = b / 64; }
  const int c0 = bx * 32, r0 = by * 64;
  const int tx = tid & 31, ty = tid >> 5;      // read: 32 cols x 8-row steps
#pragma unroll
  for (int i = 0; i < 64; i += 8)
    t[ty + i][tx] = in[(size_t)(r0 + ty + i) * C + c0 + tx];
  __syncthreads();
  const int ox = tid & 63, oy = tid >> 6;      // write: 64-wide output rows
#pragma unroll
  for (int j = 0; j < 32; j += 4)
    out[(size_t)(c0 + oy + j) * R + r0 + ox] = (bf16_t)t[ox][oy + j];
}

#define VMCNT(n) asm volatile("s_waitcnt vmcnt(" #n ")" ::: "memory")

// ======== 8-wave, counted-vmcnt double-buffered 128x128 GEMM core =============
// (r8 configuration restored — T2 swizzle + T4 counted vmcnt; used by ALL GEMMs)

__device__ __forceinline__ void stage8(const bf16_t* __restrict__ A,
                                       const bf16_t* __restrict__ Bt,
                                       int K, int N, int m0, int n0, int k0,
                                       bf16_t* As, bf16_t* Bs,
                                       int wave, int srow, int scol) {
#pragma unroll
  for (int i = 0; i < 2; ++i) {
    int r0 = (wave * 2 + i) * 8;
    gload16(A + (size_t)(m0 + r0 + srow) * K + k0 + scol, As + r0 * 64);
    int br = n0 + r0 + srow;
    if (br >= N) br = N - 1;
    gload16(Bt + (size_t)br * K + k0 + scol, Bs + r0 * 64);
  }
}

__device__ __forceinline__ void compute8(const bf16_t* As, const bf16_t* Bs,
                                         f32x4 (&acc)[2][4],
                                         int lane, int wr, int wc) {
  const int lm = lane & 15;
  const int sw = lm & 7;
#pragma unroll
  for (int ks = 0; ks < 2; ++ks) {
    const int ck = ((lane >> 4) + ks * 4) ^ sw;  // swizzled 16B chunk slot
    bf16x8 af[2], bfr[4];
#pragma unroll
    for (int i = 0; i < 2; ++i)
      af[i] = *(const bf16x8*)(As + (wr + i * 16 + lm) * 64 + ck * 8);
#pragma unroll
    for (int i = 0; i < 4; ++i)
      bfr[i] = *(const bf16x8*)(Bs + (wc + i * 16 + lm) * 64 + ck * 8);
#pragma unroll
    for (int mi = 0; mi < 2; ++mi)
#pragma unroll
      for (int ni = 0; ni < 4; ++ni)
        acc[mi][ni] = __builtin_amdgcn_mfma_f32_16x16x32_bf16(
            af[mi], bfr[ni], acc[mi][ni], 0, 0, 0);
  }
}

__device__ __forceinline__ void gemm128_dbuf8(const bf16_t* __restrict__ A,
                                              const bf16_t* __restrict__ Bt,
                                              int K, int N, int m0, int n0,
                                              bf16_t* lds, f32x4 (&acc)[2][4],
                                              int wave, int lane) {
  const int srow = lane >> 3;
  const int scol = ((lane & 7) ^ srow) * 8;  // pre-swizzled global source
  const int wr = (wave >> 1) * 32, wc = (wave & 1) * 64;
  bf16_t* A0 = lds;
  bf16_t* B0 = lds + 8192;
  bf16_t* A1 = lds + 16384;
  bf16_t* B1 = lds + 24576;
  const int nk = K >> 6;  // even, >= 2 (nk in {8,24,32})
  stage8(A, Bt, K, N, m0, n0, 0, A0, B0, wave, srow, scol);
  stage8(A, Bt, K, N, m0, n0, 64, A1, B1, wave, srow, scol);
  VMCNT(4);
  __builtin_amdgcn_s_barrier();
#pragma unroll 1
  for (int t = 0; t < nk; t += 2) {
    compute8(A0, B0, acc, lane, wr, wc);
    __builtin_amdgcn_s_barrier();
    if (t + 2 < nk) {
      stage8(A, Bt, K, N, m0, n0, (t + 2) << 6, A0, B0, wave, srow, scol);
      VMCNT(4);
    } else {
      VMCNT(0);
    }
    __builtin_amdgcn_s_barrier();
    compute8(A1, B1, acc, lane, wr, wc);
    if (t + 3 <= nk) {
      __builtin_amdgcn_s_barrier();
      if (t + 3 < nk) {
        stage8(A, Bt, K, N, m0, n0, (t + 3) << 6, A1, B1, wave, srow, scol);
        VMCNT(4);
      } else {
        VMCNT(0);
      }
      __builtin_amdgcn_s_barrier();
    }
  }
}

// ---- down-proj: bf16 output with col guard (N=2112) --------------------------
__global__ __launch_bounds__(512)
void gemm_dn8(const bf16_t* __restrict__ A, const bf16_t* __restrict__ Bt,
              bf16_t* __restrict__ C, int M, int N, int K) {
  __shared__ __align__(16) bf16_t lds[32768];
  const int tid = threadIdx.x;
  const int wave = tid >> 6, lane = tid & 63;
  const int m0 = blockIdx.y * 128, n0 = blockIdx.x * 128;
  const int wr = (wave >> 1) * 32, wc = (wave & 1) * 64;
  f32x4 acc[2][4] = {};
  gemm128_dbuf8(A, Bt, K, N, m0, n0, lds, acc, wave, lane);
  const int lm = lane & 15, lr = (lane >> 4) * 4;
#pragma unroll
  for (int mi = 0; mi < 2; ++mi)
#pragma unroll
    for (int ni = 0; ni < 4; ++ni) {
      int col = n0 + wc + ni * 16 + lm;
      if (col < N) {
#pragma unroll
        for (int i = 0; i < 4; ++i) {
          int row = m0 + wr + mi * 16 + lr + i;
          C[(size_t)row * N + col] = (bf16_t)acc[mi][ni][i];
        }
      }
    }
}

// ---- out-proj: f32 output (N=2048 exact) -------------------------------------
__global__ __launch_bounds__(512)
void gemm_outf8(const bf16_t* __restrict__ A, const bf16_t* __restrict__ Bt,
                float* __restrict__ C, int M, int N, int K) {
  __shared__ __align__(16) bf16_t lds[32768];
  const int tid = threadIdx.x;
  const int wave = tid >> 6, lane = tid & 63;
  const int m0 = blockIdx.y * 128, n0 = blockIdx.x * 128;
  const int wr = (wave >> 1) * 32, wc = (wave & 1) * 64;
  f32x4 acc[2][4] = {};
  gemm128_dbuf8(A, Bt, K, N, m0, n0, lds, acc, wave, lane);
  const int lm = lane & 15, lr = (lane >> 4) * 4;
#pragma unroll
  for (int mi = 0; mi < 2; ++mi)
#pragma unroll
    for (int ni = 0; ni < 4; ++ni) {
      int col = n0 + wc + ni * 16 + lm;
#pragma unroll
      for (int i = 0; i < 4; ++i) {
        int row = m0 + wr + mi * 16 + lr + i;
        C[(size_t)row * N + col] = acc[mi][ni][i];
      }
    }
}

// ---- merged q_up (fused RoPE/pack) + kv_up (fused k_nope/V-T pack) -----------
__global__ __launch_bounds__(512)
void gemm_qkvup8(const bf16_t* __restrict__ qdn, const bf16_t* __restrict__ WquT,
                 const bf16_t* __restrict__ ckvn, const bf16_t* __restrict__ WkvuT,
                 const int* __restrict__ pos, bf16_t* __restrict__ qs,
                 bf16_t* __restrict__ ks, bf16_t* __restrict__ vt) {
  __shared__ __align__(16) bf16_t lds[32768];
  const int tid = threadIdx.x;
  const int wave = tid >> 6, lane = tid & 63;
  const int m0 = blockIdx.y * 128;
  const int wr = (wave >> 1) * 32, wc = (wave & 1) * 64;
  const int lm = lane & 15, lr = (lane >> 4) * 4;
  f32x4 acc[2][4] = {};
  if (blockIdx.x < 24) {
    const int n0 = blockIdx.x * 128;
    gemm128_dbuf8(qdn, WquT, 1536, 3072, m0, n0, lds, acc, wave, lane);
    const bool rope = (((n0 + wc) / 64) % 3) == 2;
    if (rope) {
#pragma unroll
      for (int mi = 0; mi < 2; ++mi)
#pragma unroll
        for (int i = 0; i < 4; ++i) {
          int row = m0 + wr + mi * 16 + lr + i;
          float p = (float)pos[row];
#pragma unroll
          for (int nl = 0; nl < 2; ++nl) {
            int fi = nl * 16 + lm;
            float ang = p * exp2f(-(float)fi * 0.41524101186092030f);
            float sn, cs;
            sincosf(ang, &sn, &cs);
            float v0 = acc[mi][nl][i], v1 = acc[mi][nl + 2][i];
            int c = n0 + wc + nl * 16 + lm;
            int h = c / 192, d = c - h * 192;  // d = 128+fi
            bf16_t* base = qs + ((size_t)h * 2048 + row) * 192;
            base[d]      = (bf16_t)(v0 * cs - v1 * sn);
            base[d + 32] = (bf16_t)(v1 * cs + v0 * sn);
          }
        }
    } else {
#pragma unroll
      for (int mi = 0; mi < 2; ++mi)
#pragma unroll
        for (int ni = 0; ni < 4; ++ni) {
          int c = n0 + wc + ni * 16 + lm;
          int h = c / 192, d = c - h * 192;
#pragma unroll
          for (int i = 0; i < 4; ++i) {
            int row = m0 + wr + mi * 16 + lr + i;
            qs[((size_t)h * 2048 + row) * 192 + d] = (bf16_t)acc[mi][ni][i];
          }
        }
    }
  } else {
    const int n0 = (blockIdx.x - 24) * 128;
    gemm128_dbuf8(ckvn, WkvuT, 512, 4096, m0, n0, lds, acc, wave, lane);
#pragma unroll
    for (int mi = 0; mi < 2; ++mi)
#pragma unroll
      for (int ni = 0; ni < 4; ++ni) {
        int c = n0 + wc + ni * 16 + lm;
        int h = c >> 8, j = c & 255;
#pragma unroll
        for (int i = 0; i < 4; ++i) {
          int row = m0 + wr + mi * 16 + lr + i;
          bf16_t v = (bf16_t)acc[mi][ni][i];
          if (j < 128)
            ks[((size_t)h * 2048 + row) * 192 + j] = v;
          else
            vt[((size_t)h * 128 + (j - 128)) * 2048 + row] = v;
        }
      }
  }
}

// ---------------- merged: rmsnorm(q) + rmsnorm(kv) + k-rope -------------------
__global__ __launch_bounds__(256)
void normrope_k(const bf16_t* __restrict__ Cd, const float* __restrict__ qnw,
                const float* __restrict__ kvnw, const int* __restrict__ pos,
                bf16_t* __restrict__ qdn, bf16_t* __restrict__ ckvn,
                bf16_t* __restrict__ ks) {
  __shared__ float red[4];
  const int bid = blockIdx.x, tid = threadIdx.x;
  if (bid < 4096) {
    const bf16_t* xr;
    const float* W;
    bf16_t* yr;
    int C;
    if (bid < 2048) {
      xr = Cd + (size_t)bid * 2112; W = qnw; yr = qdn + (size_t)bid * 1536; C = 1536;
    } else {
      int r = bid - 2048;
      xr = Cd + (size_t)r * 2112 + 1536; W = kvnw; yr = ckvn + (size_t)r * 512; C = 512;
    }
    int nch = C >> 3;
    bool act = tid < nch;
    float xv[8];
    float ss = 0.f;
    if (act) {
      bf16x8 v = *(const bf16x8*)(xr + tid * 8);
#pragma unroll
      for (int i = 0; i < 8; ++i) { xv[i] = (float)v[i]; ss += xv[i] * xv[i]; }
    }
#pragma unroll
    for (int off = 1; off < 64; off <<= 1) ss += __shfl_xor(ss, off, 64);
    if ((tid & 63) == 0) red[tid >> 6] = ss;
    __syncthreads();
    float tot = red[0] + red[1] + red[2] + red[3];
    float rs = rsqrtf(tot / (float)C + 1e-6f);
    if (act) {
      bf16x8 o;
#pragma unroll
      for (int i = 0; i < 8; ++i) {
        bf16_t nb = (bf16_t)(xv[i] * rs);
        o[i] = (bf16_t)((float)nb * W[tid * 8 + i]);
      }
      *(bf16x8*)(yr + tid * 8) = o;
    }
  } else {
    int s = bid - 4096, d = tid;
    if (d < 64) {
      float v = (float)Cd[(size_t)s * 2112 + 2048 + d];
      int fi = d & 31;
      float p = (float)pos[s];
      float ang = p * exp2f(-(float)fi * 0.415241011860920295f);
      float sn = sinf(ang), co = cosf(ang);
      float other = (float)Cd[(size_t)s * 2112 + 2048 + (d < 32 ? d + 32 : d - 32)];
      v = (d < 32) ? v * co - other * sn : v * co + other * sn;
      bf16_t bv = (bf16_t)v;
#pragma unroll
      for (int h = 0; h < 16; ++h)
        ks[((size_t)h * 2048 + s) * 192 + 128 + d] = bv;
    }
  }
}

// ---------------- flash attention (round-8 body, 56.3us known-good) -----------
__global__ __launch_bounds__(256, 2)
void attn3_k(const bf16_t* __restrict__ Q, const bf16_t* __restrict__ Kst,
             const bf16_t* __restrict__ Vt, bf16_t* __restrict__ O,
             float* __restrict__ pbuf) {
  __shared__ __align__(16) bf16_t Ks[64 * 192];
  __shared__ __align__(16) bf16_t Vs[144 * 64];
  __shared__ __align__(16) bf16_t Ps[4][32 * 72];
  const int bid = blockIdx.x;
  int h, T, kbeg, kend, sp = 1;
  bool direct = false;
  if (bid < 128) {            // heavy pair-member
    h = bid >> 3; int u = bid & 7; int up = u >> 1;
    if ((u & 1) == 0) { T = 7 - up;  kbeg = 0;  kend = 2 * T + 2; direct = true; }
    else              { T = 15 - up; kbeg = 16; kend = 2 * T + 2; }
  } else if (bid < 256) {     // single: chunk0 of T>=8
    h = (bid - 128) >> 3; T = 8 + ((bid - 128) & 7); kbeg = 0; kend = 16; sp = 0;
  } else {                    // light pair-member
    h = (bid - 256) >> 3; int u = (bid - 256) & 7; int up = u >> 1;
    if ((u & 1) == 0) { T = up;     kbeg = 0;  kend = 2 * T + 2; direct = true; }
    else              { T = 8 + up; kbeg = 16; kend = 2 * T + 2; }
  }
  const int q0 = T * 128;
  const int tid = threadIdx.x, wave = tid >> 6, lane = tid & 63;
  const int lm = lane & 15, lg = lane >> 4;
  const bf16_t* Qh = Q + (size_t)h * 2048 * 192;
  const bf16_t* Kh = Kst + (size_t)h * 2048 * 192;
  const bf16_t* Vh = Vt + (size_t)h * 128 * 2048;
  const float sc = 0.08838834764831845f * LOG2E;

  bf16x8 aq[2][6];
#pragma unroll
  for (int g = 0; g < 2; ++g)
#pragma unroll
    for (int tt = 0; tt < 6; ++tt)
      aq[g][tt] = *(const bf16x8*)(Qh +
          (size_t)(q0 + wave * 32 + g * 16 + lm) * 192 + tt * 32 + lg * 8);

#pragma unroll
  for (int w = 0; w < 4; ++w) {
    int idx = w * 256 + tid;
    Vs[128 * 64 + idx] = (bf16_t)(idx < 64 ? 1.0f : 0.0f);
  }

  int kr[6], kc8[6], vr[4], vc8[4];
#pragma unroll
  for (int w = 0; w < 6; ++w) {
    int s = (wave * 6 + w) * 64 + lane;
    kr[w] = s / 24;
    kc8[w] = ((s % 24) ^ (kr[w] & 7)) * 8;
  }
#pragma unroll
  for (int w = 0; w < 4; ++w) {
    int s = (wave * 4 + w) * 64 + lane;
    vr[w] = s >> 3;
    vc8[w] = ((s & 7) ^ (vr[w] & 7)) * 8;
  }

  bf16x8 kstg[6], vstg[4];
  const int kb0 = kbeg * 64;
#pragma unroll
  for (int w = 0; w < 6; ++w)
    kstg[w] = *(const bf16x8*)(Kh + (size_t)(kb0 + kr[w]) * 192 + kc8[w]);
#pragma unroll
  for (int w = 0; w < 4; ++w)
    vstg[w] = *(const bf16x8*)(Vh + (size_t)vr[w] * 2048 + kb0 + vc8[w]);

  f32x4 o[2][9] = {};

  for (int kt = kbeg; kt < kend; ++kt) {
    const int k0 = kt * 64;
    if (kt != kbeg) __syncthreads();
#pragma unroll
    for (int w = 0; w < 6; ++w)
      *(bf16x8*)(Ks + ((wave * 6 + w) * 64 + lane) * 8) = kstg[w];
#pragma unroll
    for (int w = 0; w < 4; ++w)
      *(bf16x8*)(Vs + ((wave * 4 + w) * 64 + lane) * 8) = vstg[w];
    __syncthreads();

    if (kt + 1 < kend) {
      const int k1 = k0 + 64;
#pragma unroll
      for (int w = 0; w < 6; ++w)
        kstg[w] = *(const bf16x8*)(Kh + (size_t)(k1 + kr[w]) * 192 + kc8[w]);
#pragma unroll
      for (int w = 0; w < 4; ++w)
        vstg[w] = *(const bf16x8*)(Vh + (size_t)vr[w] * 2048 + k1 + vc8[w]);
    }

    // QK^T, SWAPPED operands: sa[g][ct] = C[k][q] (k-rows, q-cols).
    f32x4 sa[2][4] = {};
    __builtin_amdgcn_s_setprio(1);
#pragma unroll
    for (int ct = 0; ct < 4; ++ct) {
#pragma unroll
      for (int tt = 0; tt < 6; ++tt) {
        int cc = (tt * 4 + lg) ^ (lm & 7);
        bf16x8 bk = *(const bf16x8*)(Ks + (ct * 16 + lm) * 192 + cc * 8);
        sa[0][ct] = __builtin_amdgcn_mfma_f32_16x16x32_bf16(bk, aq[0][tt], sa[0][ct], 0, 0, 0);
        sa[1][ct] = __builtin_amdgcn_mfma_f32_16x16x32_bf16(bk, aq[1][tt], sa[1][ct], 0, 0, 0);
      }
    }
    __builtin_amdgcn_s_setprio(0);

    // P = exp2(sa*sc), masked, packed to b64 writes (4 k-contiguous per lane).
    bf16_t* Pw = Ps[wave];
    const bool diag = (kt >= 2 * T);
#pragma unroll
    for (int g = 0; g < 2; ++g) {
      const int gq = q0 + wave * 32 + g * 16 + lm;  // this lane's q-row
#pragma unroll
      for (int ct = 0; ct < 4; ++ct) {
        bf16x4 pk;
#pragma unroll
        for (int i = 0; i < 4; ++i) {
          float p = exp2f(sa[g][ct][i] * sc);
          if (diag && (k0 + ct * 16 + lg * 4 + i > gq)) p = 0.f;
          pk[i] = (bf16_t)p;
        }
        *(bf16x4*)(Pw + (g * 16 + lm) * 72 + ct * 16 + lg * 4) = pk;
      }
    }
    __builtin_amdgcn_s_waitcnt(0xC07F);

    __builtin_amdgcn_s_setprio(1);
#pragma unroll
    for (int ks2 = 0; ks2 < 2; ++ks2) {
      bf16x8 ap0 = *(const bf16x8*)(Pw + lm * 72 + ks2 * 32 + lg * 8);
      bf16x8 ap1 = *(const bf16x8*)(Pw + (16 + lm) * 72 + ks2 * 32 + lg * 8);
#pragma unroll
      for (int nt = 0; nt < 9; ++nt) {
        int rowv = nt * 16 + lm;
        int cc = (ks2 * 4 + lg) ^ (lm & 7);
        bf16x8 bv = *(const bf16x8*)(Vs + rowv * 64 + cc * 8);
        o[0][nt] = __builtin_amdgcn_mfma_f32_16x16x32_bf16(ap0, bv, o[0][nt], 0, 0, 0);
        o[1][nt] = __builtin_amdgcn_mfma_f32_16x16x32_bf16(ap1, bv, o[1][nt], 0, 0, 0);
      }
    }
    __builtin_amdgcn_s_setprio(0);
  }

  if (direct) {
#pragma unroll
    for (int g = 0; g < 2; ++g)
#pragma unroll
      for (int i = 0; i < 4; ++i) {
        float l = __shfl(o[g][8][i], (lane & 48), 64);
        float inv = 1.f / l;
        int row = q0 + wave * 32 + g * 16 + lg * 4 + i;
#pragma unroll
        for (int nt = 0; nt < 8; ++nt)
          O[(size_t)row * 2048 + h * 128 + nt * 16 + lm] = (bf16_t)(o[g][nt][i] * inv);
      }
  } else {
    float* P = pbuf + ((size_t)(h * 8 + (T - 8)) * 2 + sp) * 16896;
#pragma unroll
    for (int g = 0; g < 2; ++g)
#pragma unroll
      for (int i = 0; i < 4; ++i) {
        int r = wave * 32 + g * 16 + lg * 4 + i;  // 0..127
#pragma unroll
        for (int nt = 0; nt < 8; ++nt)
          P[r * 132 + nt * 16 + lm] = o[g][nt][i];
        if (lm == 0) P[r * 132 + 128] = o[g][8][i];
      }
  }
}

// ---------------- split-K combine: O = (p0+p1)/(l0+l1) ------------------------
__global__ __launch_bounds__(256)
void combine_k(const float* __restrict__ pbuf, bf16_t* __restrict__ O) {
  const int b = blockIdx.x, tid = threadIdx.x;
  const int h = b >> 3, tt = b & 7;
  const int r = tid >> 1, c0 = (tid & 1) * 64;
  const float* p0 = pbuf + ((size_t)(h * 8 + tt) * 2) * 16896 + r * 132;
  const float* p1 = p0 + 16896;
  const float inv = 1.f / (p0[128] + p1[128]);
  const int row = (8 + tt) * 128 + r;
  bf16_t* dst = O + (size_t)row * 2048 + h * 128 + c0;
#pragma unroll
  for (int i = 0; i < 64; i += 4) {
    float4 a = *(const float4*)(p0 + c0 + i);
    float4 c = *(const float4*)(p1 + c0 + i);
    bf16x4 v;
    v[0] = (bf16_t)((a.x + c.x) * inv);
    v[1] = (bf16_t)((a.y + c.y) * inv);
    v[2] = (bf16_t)((a.z + c.z) * inv);
    v[3] = (bf16_t)((a.w + c.w) * inv);
    *(bf16x4*)(dst + i) = v;
  }
}

// ------------------------------------------------------------------------------
// Arena (bf16 elements), lifetime-packed (unchanged):
//   A @0         (4,194,304): xb (dies after dn8)  -> attb (born at attn)
//   B @4194304   (4,325,376): WdT (dies after dn8) -> qdn (dies after qkvup)
//   C @8519680   (4,718,592): WquT (dies after qkvup)
//   D @13238272  (2,097,152): WkvuT (dies after qkvup)
//     pbuf (f32, 17.3MB) overlays B+C+D byte span during attn
//   E @15335424  (4,194,304): WoutT
//   F @19529728  (4,325,376): Cdown (dies after normrope) -> vt
//   G @23855104  (6,291,456): qs
//   H @30146560  (6,291,456): ks
//   I @36438016  (1,048,576): ckvn
extern "C" void kernel_launch(void* const* d_in, const int* in_sizes, int n_in,
                              void* d_out, int out_size, void* d_ws, size_t ws_size,
                              hipStream_t stream) {
  const float* x    = (const float*)d_in[0];
  const int*   pos  = (const int*)d_in[1];
  const float* Wqd  = (const float*)d_in[3];
  const float* qnw  = (const float*)d_in[4];
  const float* Wqu  = (const float*)d_in[5];
  const float* Wkvd = (const float*)d_in[6];
  const float* kvnw = (const float*)d_in[7];
  const float* Wkvu = (const float*)d_in[8];
  const float* Wout = (const float*)d_in[9];
  float* out = (float*)d_out;

  bf16_t* arena = (bf16_t*)d_ws;
  bf16_t* xb    = arena;                // region A
  bf16_t* attb  = arena;                // region A (after xb dies)
  bf16_t* WdT   = arena + 4194304;      // region B
  bf16_t* qdn   = arena + 4194304;      // region B (after WdT dies)
  bf16_t* WquT  = arena + 8519680;      // region C
  bf16_t* WkvuT = arena + 13238272;     // region D
  float*  pbuf  = (float*)(arena + 4194304);  // B..D span, live only in attn
  bf16_t* WoutT = arena + 15335424;     // region E
  bf16_t* Cdown = arena + 19529728;     // region F
  bf16_t* vt    = arena + 19529728;     // region F (after Cdown dies)
  bf16_t* qs    = arena + 23855104;     // region G
  bf16_t* ks    = arena + 30146560;     // region H
  bf16_t* ckvn  = arena + 36438016;     // region I

  // 1) fused prep: xconv + all 5 weight transposes (128B-write tiles)
  prep_k<<<dim3(11584), 256, 0, stream>>>(x, Wqd, Wkvd, Wqu, Wkvu, Wout,
                                          xb, WdT, WquT, WkvuT, WoutT);

  // 2) fused down-projection: [q_down | kv_down], Wt = [2112][2048]
  gemm_dn8<<<dim3(17, 16), 512, 0, stream>>>(xb, WdT, Cdown, 2048, 2112, 2048);

  // 3) norms + k rope
  normrope_k<<<dim3(6144), 256, 0, stream>>>(Cdown, qnw, kvnw, pos, qdn, ckvn, ks);

  // 4) merged q_up + kv_up (128x128 core, 896 blocks)
  gemm_qkvup8<<<dim3(56, 16), 512, 0, stream>>>(qdn, WquT, ckvn, WkvuT, pos,
                                                qs, ks, vt);

  // 5) attention (round-8 body)
  attn3_k<<<dim3(384), 256, 0, stream>>>(qs, ks, vt, attb, pbuf);

  // 6) combine split-tile partials for rows 1024..2047
  combine_k<<<dim3(128), 256, 0, stream>>>(pbuf, attb);

  // 7) output projection (f32 out)
  gemm_outf8<<<dim3(16, 16), 512, 0, stream>>>(attb, WoutT, out, 2048, 2048, 2048);
}